// Round 20
// baseline (97.614 us; speedup 1.0000x reference)
//
#include <hip/hip_runtime.h>
#include <hip/hip_bf16.h>

#define NPIX (1 << 20)
#define HDIM 1024
#define NREG 64          // regions: img*8 + (tile&7)
#define REGCAP 4096      // slots per region
#define NSTRIDE 17       // bank-padded node stride (row*17+rid)

#define WBAR() __builtin_amdgcn_wave_barrier()

// ============ slot-level union-find (global, union-by-min) ============
__device__ __forceinline__ int find_f(int* F, int x) {
    for (;;) {
        int p = F[x];
        if (p == x) return x;
        int gp = F[p];
        if (gp == p) return p;
        F[x] = gp;   // path halving, benign race
        x = gp;
    }
}
__device__ __forceinline__ void unite_f(int* F, int a, int b) {
    a = find_f(F, a); b = find_f(F, b);
    while (a != b) {
        if (a < b) { int t = a; a = b; b = t; }
        int old = atomicCAS(&F[a], a, b);
        if (old == a) return;
        a = find_f(F, old); b = find_f(F, b);
    }
}

// ============ LDS union-find over run nodes (id = row*17 + k) ============
__device__ __forceinline__ int find_r(int* R, int n) {
    int p = R[n];
    while (p != n) {
        int gp = R[p];
        if (gp == p) return p;
        R[n] = gp;
        n = gp;
        p = R[n];
    }
    return n;
}
__device__ __forceinline__ void unite_r(int* R, int a, int b) {
    a = find_r(R, a); b = find_r(R, b);
    while (a != b) {
        if (a < b) { int t = a; a = b; b = t; }
        int old = atomicCAS(&R[a], a, b);
        if (old == a) return;
        a = find_r(R, old); b = find_r(R, b);
    }
}

// component c of a float4 with COMPILE-TIME c (loops fully unrolled)
__device__ __forceinline__ float f4c(const float4& v, int c) {
    return c == 0 ? v.x : (c == 1 ? v.y : (c == 2 ? v.z : v.w));
}

// ============ phase A: 4 tiles/block, one tile per WAVE, interleaved ======
// vs R19: P4 unions run in 5 TREE ROUNDS (boundary rr active in round
// t = ctz(rr+1)). Within a round active boundaries connect disjoint row
// blocks -> LDS CAS contention drops from wave-wide to 2-way.
__global__ __launch_bounds__(256, 8) void local_k(
        const float4* __restrict__ pred4, const float4* __restrict__ targ4,
        int* __restrict__ edges, int* __restrict__ F,
        float2* __restrict__ fragSums,
        int* __restrict__ fragCnt, int nwg) {
    int wid = threadIdx.x >> 6;
    int l   = threadIdx.x & 63;
    int tile = wid * nwg + blockIdx.x;     // interleaved: block mixes 4 distant tiles
    int img = tile >> 10;
    int ty = (tile >> 5) & 31, tx = tile & 31;
    int r = l >> 1, h = l & 1;

    __shared__ int s_ruf[4][544];
    __shared__ float2 s_su[4][544];        // (inter, union) per run node
    int*    ruf = &s_ruf[wid][0];
    float2* su2 = &s_su[wid][0];
    float*  suf = (float*)su2;

    int rowg = img * HDIM + ty * 32 + r;
    int qb = rowg * 256 + tx * 8 + h * 4;
    int ebase = tile * 128;

    float4 Pq[4], Tq[4];
    #pragma unroll
    for (int q = 0; q < 4; ++q) { Pq[q] = pred4[qb + q]; Tq[q] = targ4[qb + q]; }

    unsigned hm = 0;
    #pragma unroll
    for (int j = 0; j < 16; ++j) {
        float s = f4c(Pq[j >> 2], j & 3) + f4c(Tq[j >> 2], j & 3);
        if (s > 0.f) hm |= 1u << j;
    }
    unsigned m = hm << (h * 16);
    m |= __shfl_xor(m, 1);                 // full 32-bit row mask on both lanes
    unsigned st = m & ~(m << 1);           // run starts
    int nrun = __popc(st);

    if (__ballot(m != 0) == 0ull) {        // empty tile: -1 edges, 2 stores/lane
        edges[ebase + l] = -1;             // L(0..31) | R(32..63)
        edges[ebase + 64 + l] = -1;        // T(64..95) | B(96..127)
        return;
    }

    // ---- sparse ruf init: only valid run nodes ----
    #pragma unroll
    for (int k = 0; k < 8; ++k) {
        int ridx = k * 2 + h;
        if (ridx < nrun) ruf[r * NSTRIDE + ridx] = r * NSTRIDE + ridx;
    }

    // ---- P3a: per-run sums (s,i recomputed on the fly); straddler in regs ----
    int nrun0 = __popc(st & 0xFFFFu);
    bool strad = ((m >> 15) & 1) && ((m >> 16) & 1);
    float ai = 0.f, au = 0.f, fi = 0.f, fu = 0.f;
    int rid = h ? (nrun0 - 1) : -1;
    bool in = false;
    #pragma unroll
    for (int j = 0; j < 16; ++j) {
        if ((hm >> j) & 1) {
            float p = f4c(Pq[j >> 2], j & 3), t = f4c(Tq[j >> 2], j & 3);
            float sj = p + t, ij = p * t;
            int x = h * 16 + j;
            if ((st >> x) & 1) {
                if (in) su2[r*NSTRIDE+rid] = make_float2(ai, au);
                ++rid; ai = 0.f; au = 0.f; in = true;
            }
            if (in) { ai += ij; au += sj; }
            else    { fi += ij; fu += sj; }   // leading continuation (h=1)
        }
    }
    float gi = __shfl_xor(fi, 1), gu = __shfl_xor(fu, 1);
    if (in) {
        if (h == 0 && strad) { ai += gi; au += gu; }
        su2[r*NSTRIDE+rid] = make_float2(ai, au);
    }
    WBAR();
    // ---- P4: vertical run unions in 5 tree rounds (low contention) ----
    {
        int bsrc = (l & ~1) + 2; if (bsrc > 63) bsrc = 63;
        unsigned mb = __shfl(m, bsrc);
        unsigned stb = mb & ~(mb << 1);
        unsigned o = m & mb;
        unsigned osAll = o & ~(o << 1);
        osAll &= h ? 0xFFFF0000u : 0x0000FFFFu;
        #pragma unroll
        for (int t = 0; t < 5; ++t) {
            // boundary between rows r and r+1 is active in round t = ctz(r+1)
            if (l < 62 && ((unsigned)(r + 1) & ((2u << t) - 1)) == (1u << t)) {
                unsigned os = osAll;
                while (os) {
                    int x = __ffs(os) - 1; os &= os - 1;
                    unsigned below = (2u << x) - 1;
                    unite_r(ruf, r * NSTRIDE + __popc(st & below) - 1,
                                 (r + 1) * NSTRIDE + __popc(stb & below) - 1);
                }
            }
            WBAR();
        }
    }
    WBAR();
    // ---- P5: flatten to depth<=1 + fold run sums into roots (b64 read) ----
    #pragma unroll
    for (int k = 0; k < 8; ++k) {
        int ridx = k * 2 + h;
        int n = r * NSTRIDE + ridx;
        if (ridx < nrun) {
            int root = find_r(ruf, n);
            if (root != n) {
                float2 v = su2[n];
                ruf[n] = root;
                atomicAdd(&suf[2*root],   v.x);
                atomicAdd(&suf[2*root+1], v.y);
            }
        }
    }
    WBAR();
    // ---- P7: slot alloc; root-ness re-derived from LDS ----
    {
        unsigned rootmask = 0; int mycnt = 0;
        #pragma unroll
        for (int k = 0; k < 8; ++k) {
            int ridx = k * 2 + h;
            int n = r * NSTRIDE + ridx;
            if (ridx < nrun && ruf[n] == n) { rootmask |= 1u << k; ++mycnt; }
        }
        int inc = mycnt;
        #pragma unroll
        for (int d = 1; d < 64; d <<= 1) {
            int t = __shfl_up(inc, d);
            if (l >= d) inc += t;
        }
        int cidx = (img << 3) | (tile & 7);
        int base = 0;
        if (l == 63) base = atomicAdd(&fragCnt[cidx], inc);
        base = __shfl(base, 63);
        int o = base + inc - mycnt;
        #pragma unroll
        for (int k = 0; k < 8; ++k) {
            if ((rootmask >> k) & 1) {
                int n = r * NSTRIDE + k * 2 + h;
                int off = o++;
                if (off < REGCAP) {
                    int slot = cidx * REGCAP + off;
                    F[slot] = slot;
                    fragSums[slot] = su2[n];        // single b64 LDS read
                    ruf[n] = ~slot;
                } else ruf[n] = ~0;
            }
        }
    }
    WBAR();
    // ---- edges: L/R by row-pair, T/B one pixel per lane ----
    {
        int s = -1;
        if (h == 0) {
            if (m & 1u) { int v = ruf[r * NSTRIDE]; s = (v < 0) ? ~v : ~ruf[v]; }
            edges[ebase + r] = s;
        } else {
            if (m >> 31) { int v = ruf[r * NSTRIDE + nrun - 1]; s = (v < 0) ? ~v : ~ruf[v]; }
            edges[ebase + 32 + r] = s;
        }
    }
    {
        int srcl = (l < 32) ? 0 : 62;      // lane holding full mask of row 0 / 31
        unsigned mm = __shfl(m, srcl);
        int x = l & 31;
        int s = -1;
        if ((mm >> x) & 1) {
            unsigned stt = mm & ~(mm << 1);
            int row = (l < 32) ? 0 : 31;
            int node = row * NSTRIDE + __popc(stt & ((2u << x) - 1)) - 1;
            int v = ruf[node];
            s = (v < 0) ? ~v : ~ruf[v];
        }
        edges[ebase + 64 + l] = s;
    }
}

// ============ phase B: boundary slot unions ============
__global__ void bound_k(const int* __restrict__ edges, int* __restrict__ F) {
    int img = blockIdx.x / 248;
    int e = (blockIdx.x % 248) * 256 + threadIdx.x;
    int sA, sB;
    if (e < 31744) {            // vertical boundary: tx=k <-> k+1, row y
        int k = e >> 10, y = e & 1023;
        int ty = y >> 5, rr = y & 31;
        int tileA = img * 1024 + ty * 32 + k;
        sA = edges[tileA * 128 + 32 + rr];
        sB = edges[(tileA + 1) * 128 + rr];
    } else {                    // horizontal boundary
        int e2 = e - 31744;
        int k = e2 >> 10, x = e2 & 1023;
        int tileA = img * 1024 + k * 32 + (x >> 5);
        sA = edges[tileA * 128 + 96 + (x & 31)];
        sB = edges[(tileA + 32) * 128 + 64 + (x & 31)];
    }
    if (sA >= 0 && sB >= 0) unite_f(F, sA, sB);
}

// ============ phase C: fold donors (4 sub-blocks per region = 256 blocks) ==
__global__ void merge_frag_k(int* __restrict__ F, float* __restrict__ fragSums,
                             const int* __restrict__ fragCnt, int C) {
    int cidx = blockIdx.x >> 2, sub = blockIdx.x & 3;
    if (cidx >= C * 8) return;
    int cnt = fragCnt[cidx]; if (cnt > REGCAP) cnt = REGCAP;
    int quarter = (cnt + 3) >> 2;
    int lo = sub * quarter;
    int hi = lo + quarter; if (hi > cnt) hi = cnt;
    for (int off = lo + threadIdx.x; off < hi; off += 256) {
        int i = cidx * REGCAP + off;
        int rt = find_f(F, i);
        if (rt != i) {
            float2 d = ((const float2*)fragSums)[i];
            unsafeAtomicAdd(&fragSums[2 * rt], d.x);
            unsafeAtomicAdd(&fragSums[2 * rt + 1], d.y);
        }
    }
}

// ============ phase D: dice (4 sub-blocks per region), WRITE partials ======
__global__ void dice_frag_k(const int* __restrict__ F, const float2* __restrict__ fragSums,
                            const int* __restrict__ fragCnt,
                            float* __restrict__ partials, int b0, int C) {
    int cidx = blockIdx.x >> 2, sub = blockIdx.x & 3;
    if (cidx >= C * 8) return;
    int cnt = fragCnt[cidx]; if (cnt > REGCAP) cnt = REGCAP;
    int quarter = (cnt + 3) >> 2;
    int lo = sub * quarter;
    int hi = lo + quarter; if (hi > cnt) hi = cnt;
    float ds = 0.f, dn = 0.f;
    for (int off = lo + threadIdx.x; off < hi; off += 256) {
        int i = cidx * REGCAP + off;
        if (F[i] != i) continue;             // not a final root
        float2 s2 = fragSums[i];
        ds += (2.f * s2.x + 1e-6f) / (s2.y + 1e-6f);
        dn += 1.f;
    }
    #pragma unroll
    for (int d = 32; d > 0; d >>= 1) {
        ds += __shfl_down(ds, d);
        dn += __shfl_down(dn, d);
    }
    __shared__ float s_s[4], s_n[4];
    int wv = threadIdx.x >> 6;
    if ((threadIdx.x & 63) == 0) { s_s[wv] = ds; s_n[wv] = dn; }
    __syncthreads();
    if (threadIdx.x == 0) {
        int img = b0 + (cidx >> 3);
        int slotp = ((cidx & 7) << 2) | sub;     // 32 partial pairs per image
        partials[img * 64 + slotp * 2]     = s_s[0] + s_s[1] + s_s[2] + s_s[3];
        partials[img * 64 + slotp * 2 + 1] = s_n[0] + s_n[1] + s_n[2] + s_n[3];
    }
}

__global__ void zero_k(int* __restrict__ fragCnt) {
    if (threadIdx.x < NREG) fragCnt[threadIdx.x] = 0;
}

__global__ void final_k(const float* __restrict__ partials, float* __restrict__ out, int B) {
    if (threadIdx.x == 0 && blockIdx.x == 0) {
        float acc = 0.f;
        for (int img = 0; img < B; ++img) {
            float s = 0.f, n = 0.f;
            for (int p = 0; p < 32; ++p) {
                s += partials[img * 64 + p * 2];
                n += partials[img * 64 + p * 2 + 1];
            }
            acc += (n > 0.f) ? (1.f - s / n) : 1.f;
        }
        out[0] = acc / (float)B;
    }
}

// ============ launch ============
extern "C" void kernel_launch(void* const* d_in, const int* in_sizes, int n_in,
                              void* d_out, int out_size, void* d_ws, size_t ws_size,
                              hipStream_t stream) {
    const float* pred = (const float*)d_in[0];
    const float* targ = (const float*)d_in[1];
    float* out = (float*)d_out;
    int B = in_sizes[0] / NPIX;
    if (B < 1) B = 1;

    char* ws = (char*)d_ws;
    size_t off = 0;
    float* partials = (float*)ws;                       // B*64 floats
    off += ((size_t)B * 64 * sizeof(float) + 255) & ~(size_t)255;
    int* fragCnt = (int*)(ws + off);
    off += ((size_t)NREG * 4 + 255) & ~(size_t)255;

    // fixed slot pool: F 1MB + fragSums 2MB
    const size_t NSLOT = (size_t)NREG * REGCAP;
    int*    F        = (int*)   (ws + off); off += NSLOT * 4;
    float2* fragSums = (float2*)(ws + off); off += NSLOT * 8;
    size_t fixed = off;

    const size_t perImg = (size_t)1024 * 128 * 4;       // edges only (512KB)
    int maxC = 1;
    if (ws_size > fixed + perImg) {
        size_t mm = (ws_size - fixed) / perImg;
        maxC = (int)(mm < (size_t)B ? mm : (size_t)B);
        if (maxC < 1) maxC = 1;
        if (maxC > 8) maxC = 8;
    }
    int* edgesA = (int*)(ws + off);

    for (int b0 = 0; b0 < B; b0 += maxC) {
        int C = (B - b0 < maxC) ? (B - b0) : maxC;
        const float* pc = pred + (size_t)b0 * NPIX;
        const float* tc = targ + (size_t)b0 * NPIX;
        int nwg = C * 256;
        zero_k<<<1, 64, 0, stream>>>(fragCnt);
        local_k<<<nwg, 256, 0, stream>>>((const float4*)pc, (const float4*)tc,
                                         edgesA, F, fragSums, fragCnt, nwg);
        bound_k<<<C * 248, 256, 0, stream>>>(edgesA, F);
        merge_frag_k<<<NREG * 4, 256, 0, stream>>>(F, (float*)fragSums, fragCnt, C);
        dice_frag_k<<<NREG * 4, 256, 0, stream>>>(F, fragSums, fragCnt, partials, b0, C);
    }

    final_k<<<1, 64, 0, stream>>>(partials, out, B);
}

// Round 21
// 93.238 us; speedup vs baseline: 1.0469x; 1.0469x over previous
//
#include <hip/hip_runtime.h>
#include <hip/hip_bf16.h>

#define NPIX (1 << 20)
#define HDIM 1024
#define NREG 64          // regions: img*8 + (tile&7)
#define REGCAP 4096      // slots per region
#define NSTRIDE 17       // bank-padded node stride (row*17+rid)

#define WBAR() __builtin_amdgcn_wave_barrier()

// ============ slot-level union-find (global, union-by-min) ============
__device__ __forceinline__ int find_f(int* F, int x) {
    for (;;) {
        int p = F[x];
        if (p == x) return x;
        int gp = F[p];
        if (gp == p) return p;
        F[x] = gp;   // path halving, benign race
        x = gp;
    }
}
__device__ __forceinline__ void unite_f(int* F, int a, int b) {
    a = find_f(F, a); b = find_f(F, b);
    while (a != b) {
        if (a < b) { int t = a; a = b; b = t; }
        int old = atomicCAS(&F[a], a, b);
        if (old == a) return;
        a = find_f(F, old); b = find_f(F, b);
    }
}

// ============ LDS union-find over run nodes (id = row*17 + k) ============
__device__ __forceinline__ int find_r(int* R, int n) {
    int p = R[n];
    while (p != n) {
        int gp = R[p];
        if (gp == p) return p;
        R[n] = gp;
        n = gp;
        p = R[n];
    }
    return n;
}
__device__ __forceinline__ void unite_r(int* R, int a, int b) {
    a = find_r(R, a); b = find_r(R, b);
    while (a != b) {
        if (a < b) { int t = a; a = b; b = t; }
        int old = atomicCAS(&R[a], a, b);
        if (old == a) return;
        a = find_r(R, old); b = find_r(R, b);
    }
}

// component c of a float4 with COMPILE-TIME c (loops fully unrolled)
__device__ __forceinline__ float f4c(const float4& v, int c) {
    return c == 0 ? v.x : (c == 1 ? v.y : (c == 2 ? v.z : v.w));
}

// ============ phase A: 4 tiles/block, one tile per WAVE, interleaved ======
// R19 proven version: stride-17 bank padding, sparse ruf init, fused
// float2 run sums, single-pass P4 unions.
__global__ __launch_bounds__(256, 8) void local_k(
        const float4* __restrict__ pred4, const float4* __restrict__ targ4,
        int* __restrict__ edges, int* __restrict__ F,
        float2* __restrict__ fragSums,
        int* __restrict__ fragCnt, int nwg) {
    int wid = threadIdx.x >> 6;
    int l   = threadIdx.x & 63;
    int tile = wid * nwg + blockIdx.x;     // interleaved: block mixes 4 distant tiles
    int img = tile >> 10;
    int ty = (tile >> 5) & 31, tx = tile & 31;
    int r = l >> 1, h = l & 1;

    __shared__ int s_ruf[4][544];
    __shared__ float2 s_su[4][544];        // (inter, union) per run node
    int*    ruf = &s_ruf[wid][0];
    float2* su2 = &s_su[wid][0];
    float*  suf = (float*)su2;

    int rowg = img * HDIM + ty * 32 + r;
    int qb = rowg * 256 + tx * 8 + h * 4;
    int ebase = tile * 128;

    float4 Pq[4], Tq[4];
    #pragma unroll
    for (int q = 0; q < 4; ++q) { Pq[q] = pred4[qb + q]; Tq[q] = targ4[qb + q]; }

    unsigned hm = 0;
    #pragma unroll
    for (int j = 0; j < 16; ++j) {
        float s = f4c(Pq[j >> 2], j & 3) + f4c(Tq[j >> 2], j & 3);
        if (s > 0.f) hm |= 1u << j;
    }
    unsigned m = hm << (h * 16);
    m |= __shfl_xor(m, 1);                 // full 32-bit row mask on both lanes
    unsigned st = m & ~(m << 1);           // run starts
    int nrun = __popc(st);

    if (__ballot(m != 0) == 0ull) {        // empty tile: -1 edges, 2 stores/lane
        edges[ebase + l] = -1;             // L(0..31) | R(32..63)
        edges[ebase + 64 + l] = -1;        // T(64..95) | B(96..127)
        return;
    }

    // ---- sparse ruf init: only valid run nodes ----
    #pragma unroll
    for (int k = 0; k < 8; ++k) {
        int ridx = k * 2 + h;
        if (ridx < nrun) ruf[r * NSTRIDE + ridx] = r * NSTRIDE + ridx;
    }

    // ---- P3a: per-run sums (s,i recomputed on the fly); straddler in regs ----
    int nrun0 = __popc(st & 0xFFFFu);
    bool strad = ((m >> 15) & 1) && ((m >> 16) & 1);
    float ai = 0.f, au = 0.f, fi = 0.f, fu = 0.f;
    int rid = h ? (nrun0 - 1) : -1;
    bool in = false;
    #pragma unroll
    for (int j = 0; j < 16; ++j) {
        if ((hm >> j) & 1) {
            float p = f4c(Pq[j >> 2], j & 3), t = f4c(Tq[j >> 2], j & 3);
            float sj = p + t, ij = p * t;
            int x = h * 16 + j;
            if ((st >> x) & 1) {
                if (in) su2[r*NSTRIDE+rid] = make_float2(ai, au);
                ++rid; ai = 0.f; au = 0.f; in = true;
            }
            if (in) { ai += ij; au += sj; }
            else    { fi += ij; fu += sj; }   // leading continuation (h=1)
        }
    }
    float gi = __shfl_xor(fi, 1), gu = __shfl_xor(fu, 1);
    if (in) {
        if (h == 0 && strad) { ai += gi; au += gu; }
        su2[r*NSTRIDE+rid] = make_float2(ai, au);
    }
    WBAR();
    // ---- P4: vertical run unions, lane pair per row boundary ----
    {
        int bsrc = (l & ~1) + 2; if (bsrc > 63) bsrc = 63;
        unsigned mb = __shfl(m, bsrc);
        if (l < 62) {
            unsigned stb = mb & ~(mb << 1);
            unsigned o = m & mb;
            unsigned os = o & ~(o << 1);
            os &= h ? 0xFFFF0000u : 0x0000FFFFu;
            while (os) {
                int x = __ffs(os) - 1; os &= os - 1;
                unsigned below = (2u << x) - 1;
                unite_r(ruf, r * NSTRIDE + __popc(st & below) - 1,
                             (r + 1) * NSTRIDE + __popc(stb & below) - 1);
            }
        }
    }
    WBAR();
    // ---- P5: flatten to depth<=1 + fold run sums into roots (b64 read) ----
    #pragma unroll
    for (int k = 0; k < 8; ++k) {
        int ridx = k * 2 + h;
        int n = r * NSTRIDE + ridx;
        if (ridx < nrun) {
            int root = find_r(ruf, n);
            if (root != n) {
                float2 v = su2[n];
                ruf[n] = root;
                atomicAdd(&suf[2*root],   v.x);
                atomicAdd(&suf[2*root+1], v.y);
            }
        }
    }
    WBAR();
    // ---- P7: slot alloc; root-ness re-derived from LDS ----
    {
        unsigned rootmask = 0; int mycnt = 0;
        #pragma unroll
        for (int k = 0; k < 8; ++k) {
            int ridx = k * 2 + h;
            int n = r * NSTRIDE + ridx;
            if (ridx < nrun && ruf[n] == n) { rootmask |= 1u << k; ++mycnt; }
        }
        int inc = mycnt;
        #pragma unroll
        for (int d = 1; d < 64; d <<= 1) {
            int t = __shfl_up(inc, d);
            if (l >= d) inc += t;
        }
        int cidx = (img << 3) | (tile & 7);
        int base = 0;
        if (l == 63) base = atomicAdd(&fragCnt[cidx], inc);
        base = __shfl(base, 63);
        int o = base + inc - mycnt;
        #pragma unroll
        for (int k = 0; k < 8; ++k) {
            if ((rootmask >> k) & 1) {
                int n = r * NSTRIDE + k * 2 + h;
                int off = o++;
                if (off < REGCAP) {
                    int slot = cidx * REGCAP + off;
                    F[slot] = slot;
                    fragSums[slot] = su2[n];        // single b64 LDS read
                    ruf[n] = ~slot;
                } else ruf[n] = ~0;
            }
        }
    }
    WBAR();
    // ---- edges: L/R by row-pair, T/B one pixel per lane ----
    {
        int s = -1;
        if (h == 0) {
            if (m & 1u) { int v = ruf[r * NSTRIDE]; s = (v < 0) ? ~v : ~ruf[v]; }
            edges[ebase + r] = s;
        } else {
            if (m >> 31) { int v = ruf[r * NSTRIDE + nrun - 1]; s = (v < 0) ? ~v : ~ruf[v]; }
            edges[ebase + 32 + r] = s;
        }
    }
    {
        int srcl = (l < 32) ? 0 : 62;      // lane holding full mask of row 0 / 31
        unsigned mm = __shfl(m, srcl);
        int x = l & 31;
        int s = -1;
        if ((mm >> x) & 1) {
            unsigned stt = mm & ~(mm << 1);
            int row = (l < 32) ? 0 : 31;
            int node = row * NSTRIDE + __popc(stt & ((2u << x) - 1)) - 1;
            int v = ruf[node];
            s = (v < 0) ? ~v : ~ruf[v];
        }
        edges[ebase + 64 + l] = s;
    }
}

// ============ phase B: boundary slot unions ============
__global__ void bound_k(const int* __restrict__ edges, int* __restrict__ F) {
    int img = blockIdx.x / 248;
    int e = (blockIdx.x % 248) * 256 + threadIdx.x;
    int sA, sB;
    if (e < 31744) {            // vertical boundary: tx=k <-> k+1, row y
        int k = e >> 10, y = e & 1023;
        int ty = y >> 5, rr = y & 31;
        int tileA = img * 1024 + ty * 32 + k;
        sA = edges[tileA * 128 + 32 + rr];
        sB = edges[(tileA + 1) * 128 + rr];
    } else {                    // horizontal boundary
        int e2 = e - 31744;
        int k = e2 >> 10, x = e2 & 1023;
        int tileA = img * 1024 + k * 32 + (x >> 5);
        sA = edges[tileA * 128 + 96 + (x & 31)];
        sB = edges[(tileA + 32) * 128 + 64 + (x & 31)];
    }
    if (sA >= 0 && sB >= 0) unite_f(F, sA, sB);
}

// ============ phase C: fold donors (4 sub-blocks per region = 256 blocks) ==
__global__ void merge_frag_k(int* __restrict__ F, float* __restrict__ fragSums,
                             const int* __restrict__ fragCnt, int C) {
    int cidx = blockIdx.x >> 2, sub = blockIdx.x & 3;
    if (cidx >= C * 8) return;
    int cnt = fragCnt[cidx]; if (cnt > REGCAP) cnt = REGCAP;
    int quarter = (cnt + 3) >> 2;
    int lo = sub * quarter;
    int hi = lo + quarter; if (hi > cnt) hi = cnt;
    for (int off = lo + threadIdx.x; off < hi; off += 256) {
        int i = cidx * REGCAP + off;
        int rt = find_f(F, i);
        if (rt != i) {
            float2 d = ((const float2*)fragSums)[i];
            unsafeAtomicAdd(&fragSums[2 * rt], d.x);
            unsafeAtomicAdd(&fragSums[2 * rt + 1], d.y);
        }
    }
}

// ============ phase D: dice (4 sub-blocks per region), WRITE partials ======
__global__ void dice_frag_k(const int* __restrict__ F, const float2* __restrict__ fragSums,
                            const int* __restrict__ fragCnt,
                            float* __restrict__ partials, int b0, int C) {
    int cidx = blockIdx.x >> 2, sub = blockIdx.x & 3;
    if (cidx >= C * 8) return;
    int cnt = fragCnt[cidx]; if (cnt > REGCAP) cnt = REGCAP;
    int quarter = (cnt + 3) >> 2;
    int lo = sub * quarter;
    int hi = lo + quarter; if (hi > cnt) hi = cnt;
    float ds = 0.f, dn = 0.f;
    for (int off = lo + threadIdx.x; off < hi; off += 256) {
        int i = cidx * REGCAP + off;
        if (F[i] != i) continue;             // not a final root
        float2 s2 = fragSums[i];
        ds += (2.f * s2.x + 1e-6f) / (s2.y + 1e-6f);
        dn += 1.f;
    }
    #pragma unroll
    for (int d = 32; d > 0; d >>= 1) {
        ds += __shfl_down(ds, d);
        dn += __shfl_down(dn, d);
    }
    __shared__ float s_s[4], s_n[4];
    int wv = threadIdx.x >> 6;
    if ((threadIdx.x & 63) == 0) { s_s[wv] = ds; s_n[wv] = dn; }
    __syncthreads();
    if (threadIdx.x == 0) {
        int img = b0 + (cidx >> 3);
        int slotp = ((cidx & 7) << 2) | sub;     // 32 partial pairs per image
        partials[img * 64 + slotp * 2]     = s_s[0] + s_s[1] + s_s[2] + s_s[3];
        partials[img * 64 + slotp * 2 + 1] = s_n[0] + s_n[1] + s_n[2] + s_n[3];
    }
}

__global__ void final_k(const float* __restrict__ partials, float* __restrict__ out, int B) {
    if (threadIdx.x == 0 && blockIdx.x == 0) {
        float acc = 0.f;
        for (int img = 0; img < B; ++img) {
            float s = 0.f, n = 0.f;
            for (int p = 0; p < 32; ++p) {
                s += partials[img * 64 + p * 2];
                n += partials[img * 64 + p * 2 + 1];
            }
            acc += (n > 0.f) ? (1.f - s / n) : 1.f;
        }
        out[0] = acc / (float)B;
    }
}

// ============ launch ============
extern "C" void kernel_launch(void* const* d_in, const int* in_sizes, int n_in,
                              void* d_out, int out_size, void* d_ws, size_t ws_size,
                              hipStream_t stream) {
    const float* pred = (const float*)d_in[0];
    const float* targ = (const float*)d_in[1];
    float* out = (float*)d_out;
    int B = in_sizes[0] / NPIX;
    if (B < 1) B = 1;

    char* ws = (char*)d_ws;
    size_t off = 0;
    float* partials = (float*)ws;                       // B*64 floats
    off += ((size_t)B * 64 * sizeof(float) + 255) & ~(size_t)255;
    int* fragCnt = (int*)(ws + off);
    off += ((size_t)NREG * 4 + 255) & ~(size_t)255;

    // fixed slot pool: F 1MB + fragSums 2MB
    const size_t NSLOT = (size_t)NREG * REGCAP;
    int*    F        = (int*)   (ws + off); off += NSLOT * 4;
    float2* fragSums = (float2*)(ws + off); off += NSLOT * 8;
    size_t fixed = off;

    const size_t perImg = (size_t)1024 * 128 * 4;       // edges only (512KB)
    int maxC = 1;
    if (ws_size > fixed + perImg) {
        size_t mm = (ws_size - fixed) / perImg;
        maxC = (int)(mm < (size_t)B ? mm : (size_t)B);
        if (maxC < 1) maxC = 1;
        if (maxC > 8) maxC = 8;
    }
    int* edgesA = (int*)(ws + off);

    for (int b0 = 0; b0 < B; b0 += maxC) {
        int C = (B - b0 < maxC) ? (B - b0) : maxC;
        const float* pc = pred + (size_t)b0 * NPIX;
        const float* tc = targ + (size_t)b0 * NPIX;
        int nwg = C * 256;
        hipMemsetAsync(fragCnt, 0, NREG * sizeof(int), stream);   // replaces zero_k launch
        local_k<<<nwg, 256, 0, stream>>>((const float4*)pc, (const float4*)tc,
                                         edgesA, F, fragSums, fragCnt, nwg);
        bound_k<<<C * 248, 256, 0, stream>>>(edgesA, F);
        merge_frag_k<<<NREG * 4, 256, 0, stream>>>(F, (float*)fragSums, fragCnt, C);
        dice_frag_k<<<NREG * 4, 256, 0, stream>>>(F, fragSums, fragCnt, partials, b0, C);
    }

    final_k<<<1, 64, 0, stream>>>(partials, out, B);
}

// Round 22
// 91.096 us; speedup vs baseline: 1.0716x; 1.0235x over previous
//
#include <hip/hip_runtime.h>
#include <hip/hip_bf16.h>

#define NPIX (1 << 20)
#define HDIM 1024
#define NREG 64          // regions: img*8 + (tile&7)
#define REGCAP 4096      // slots per region
#define NSTRIDE 17       // bank-padded node stride (row*17+rid)

#define WBAR() __builtin_amdgcn_wave_barrier()

// ============ slot-level union-find (global, union-by-min) ============
__device__ __forceinline__ int find_f(int* F, int x) {
    for (;;) {
        int p = F[x];
        if (p == x) return x;
        int gp = F[p];
        if (gp == p) return p;
        F[x] = gp;   // path halving, benign race
        x = gp;
    }
}
__device__ __forceinline__ void unite_f(int* F, int a, int b) {
    a = find_f(F, a); b = find_f(F, b);
    while (a != b) {
        if (a < b) { int t = a; a = b; b = t; }
        int old = atomicCAS(&F[a], a, b);
        if (old == a) return;
        a = find_f(F, old); b = find_f(F, b);
    }
}

// ============ LDS union-find over run nodes (id = row*17 + k) ============
__device__ __forceinline__ int find_r(int* R, int n) {
    int p = R[n];
    while (p != n) {
        int gp = R[p];
        if (gp == p) return p;
        R[n] = gp;
        n = gp;
        p = R[n];
    }
    return n;
}
__device__ __forceinline__ void unite_r(int* R, int a, int b) {
    a = find_r(R, a); b = find_r(R, b);
    while (a != b) {
        if (a < b) { int t = a; a = b; b = t; }
        int old = atomicCAS(&R[a], a, b);
        if (old == a) return;
        a = find_r(R, old); b = find_r(R, b);
    }
}

// component c of a float4 with COMPILE-TIME c (loops fully unrolled)
__device__ __forceinline__ float f4c(const float4& v, int c) {
    return c == 0 ? v.x : (c == 1 ? v.y : (c == 2 ? v.z : v.w));
}

// ============ phase A: 4 tiles/block, one tile per WAVE, interleaved ======
// R19 proven version: stride-17 bank padding, sparse ruf init, fused
// float2 run sums, single-pass P4 unions.
__global__ __launch_bounds__(256, 8) void local_k(
        const float4* __restrict__ pred4, const float4* __restrict__ targ4,
        int* __restrict__ edges, int* __restrict__ F,
        float2* __restrict__ fragSums,
        int* __restrict__ fragCnt, int nwg) {
    int wid = threadIdx.x >> 6;
    int l   = threadIdx.x & 63;
    int tile = wid * nwg + blockIdx.x;     // interleaved: block mixes 4 distant tiles
    int img = tile >> 10;
    int ty = (tile >> 5) & 31, tx = tile & 31;
    int r = l >> 1, h = l & 1;

    __shared__ int s_ruf[4][544];
    __shared__ float2 s_su[4][544];        // (inter, union) per run node
    int*    ruf = &s_ruf[wid][0];
    float2* su2 = &s_su[wid][0];
    float*  suf = (float*)su2;

    int rowg = img * HDIM + ty * 32 + r;
    int qb = rowg * 256 + tx * 8 + h * 4;
    int ebase = tile * 128;

    float4 Pq[4], Tq[4];
    #pragma unroll
    for (int q = 0; q < 4; ++q) { Pq[q] = pred4[qb + q]; Tq[q] = targ4[qb + q]; }

    unsigned hm = 0;
    #pragma unroll
    for (int j = 0; j < 16; ++j) {
        float s = f4c(Pq[j >> 2], j & 3) + f4c(Tq[j >> 2], j & 3);
        if (s > 0.f) hm |= 1u << j;
    }
    unsigned m = hm << (h * 16);
    m |= __shfl_xor(m, 1);                 // full 32-bit row mask on both lanes
    unsigned st = m & ~(m << 1);           // run starts
    int nrun = __popc(st);

    if (__ballot(m != 0) == 0ull) {        // empty tile: -1 edges, 2 stores/lane
        edges[ebase + l] = -1;             // L(0..31) | R(32..63)
        edges[ebase + 64 + l] = -1;        // T(64..95) | B(96..127)
        return;
    }

    // ---- sparse ruf init: only valid run nodes ----
    #pragma unroll
    for (int k = 0; k < 8; ++k) {
        int ridx = k * 2 + h;
        if (ridx < nrun) ruf[r * NSTRIDE + ridx] = r * NSTRIDE + ridx;
    }

    // ---- P3a: per-run sums (s,i recomputed on the fly); straddler in regs ----
    int nrun0 = __popc(st & 0xFFFFu);
    bool strad = ((m >> 15) & 1) && ((m >> 16) & 1);
    float ai = 0.f, au = 0.f, fi = 0.f, fu = 0.f;
    int rid = h ? (nrun0 - 1) : -1;
    bool in = false;
    #pragma unroll
    for (int j = 0; j < 16; ++j) {
        if ((hm >> j) & 1) {
            float p = f4c(Pq[j >> 2], j & 3), t = f4c(Tq[j >> 2], j & 3);
            float sj = p + t, ij = p * t;
            int x = h * 16 + j;
            if ((st >> x) & 1) {
                if (in) su2[r*NSTRIDE+rid] = make_float2(ai, au);
                ++rid; ai = 0.f; au = 0.f; in = true;
            }
            if (in) { ai += ij; au += sj; }
            else    { fi += ij; fu += sj; }   // leading continuation (h=1)
        }
    }
    float gi = __shfl_xor(fi, 1), gu = __shfl_xor(fu, 1);
    if (in) {
        if (h == 0 && strad) { ai += gi; au += gu; }
        su2[r*NSTRIDE+rid] = make_float2(ai, au);
    }
    WBAR();
    // ---- P4: vertical run unions, lane pair per row boundary ----
    {
        int bsrc = (l & ~1) + 2; if (bsrc > 63) bsrc = 63;
        unsigned mb = __shfl(m, bsrc);
        if (l < 62) {
            unsigned stb = mb & ~(mb << 1);
            unsigned o = m & mb;
            unsigned os = o & ~(o << 1);
            os &= h ? 0xFFFF0000u : 0x0000FFFFu;
            while (os) {
                int x = __ffs(os) - 1; os &= os - 1;
                unsigned below = (2u << x) - 1;
                unite_r(ruf, r * NSTRIDE + __popc(st & below) - 1,
                             (r + 1) * NSTRIDE + __popc(stb & below) - 1);
            }
        }
    }
    WBAR();
    // ---- P5: flatten to depth<=1 + fold run sums into roots (b64 read) ----
    #pragma unroll
    for (int k = 0; k < 8; ++k) {
        int ridx = k * 2 + h;
        int n = r * NSTRIDE + ridx;
        if (ridx < nrun) {
            int root = find_r(ruf, n);
            if (root != n) {
                float2 v = su2[n];
                ruf[n] = root;
                atomicAdd(&suf[2*root],   v.x);
                atomicAdd(&suf[2*root+1], v.y);
            }
        }
    }
    WBAR();
    // ---- P7: slot alloc; root-ness re-derived from LDS ----
    {
        unsigned rootmask = 0; int mycnt = 0;
        #pragma unroll
        for (int k = 0; k < 8; ++k) {
            int ridx = k * 2 + h;
            int n = r * NSTRIDE + ridx;
            if (ridx < nrun && ruf[n] == n) { rootmask |= 1u << k; ++mycnt; }
        }
        int inc = mycnt;
        #pragma unroll
        for (int d = 1; d < 64; d <<= 1) {
            int t = __shfl_up(inc, d);
            if (l >= d) inc += t;
        }
        int cidx = (img << 3) | (tile & 7);
        int base = 0;
        if (l == 63) base = atomicAdd(&fragCnt[cidx], inc);
        base = __shfl(base, 63);
        int o = base + inc - mycnt;
        #pragma unroll
        for (int k = 0; k < 8; ++k) {
            if ((rootmask >> k) & 1) {
                int n = r * NSTRIDE + k * 2 + h;
                int off = o++;
                if (off < REGCAP) {
                    int slot = cidx * REGCAP + off;
                    F[slot] = slot;
                    fragSums[slot] = su2[n];        // single b64 LDS read
                    ruf[n] = ~slot;
                } else ruf[n] = ~0;
            }
        }
    }
    WBAR();
    // ---- edges: L/R by row-pair, T/B one pixel per lane ----
    {
        int s = -1;
        if (h == 0) {
            if (m & 1u) { int v = ruf[r * NSTRIDE]; s = (v < 0) ? ~v : ~ruf[v]; }
            edges[ebase + r] = s;
        } else {
            if (m >> 31) { int v = ruf[r * NSTRIDE + nrun - 1]; s = (v < 0) ? ~v : ~ruf[v]; }
            edges[ebase + 32 + r] = s;
        }
    }
    {
        int srcl = (l < 32) ? 0 : 62;      // lane holding full mask of row 0 / 31
        unsigned mm = __shfl(m, srcl);
        int x = l & 31;
        int s = -1;
        if ((mm >> x) & 1) {
            unsigned stt = mm & ~(mm << 1);
            int row = (l < 32) ? 0 : 31;
            int node = row * NSTRIDE + __popc(stt & ((2u << x) - 1)) - 1;
            int v = ruf[node];
            s = (v < 0) ? ~v : ~ruf[v];
        }
        edges[ebase + 64 + l] = s;
    }
}

// ============ phase B: boundary slot unions ============
__global__ void bound_k(const int* __restrict__ edges, int* __restrict__ F) {
    int img = blockIdx.x / 248;
    int e = (blockIdx.x % 248) * 256 + threadIdx.x;
    int sA, sB;
    if (e < 31744) {            // vertical boundary: tx=k <-> k+1, row y
        int k = e >> 10, y = e & 1023;
        int ty = y >> 5, rr = y & 31;
        int tileA = img * 1024 + ty * 32 + k;
        sA = edges[tileA * 128 + 32 + rr];
        sB = edges[(tileA + 1) * 128 + rr];
    } else {                    // horizontal boundary
        int e2 = e - 31744;
        int k = e2 >> 10, x = e2 & 1023;
        int tileA = img * 1024 + k * 32 + (x >> 5);
        sA = edges[tileA * 128 + 96 + (x & 31)];
        sB = edges[(tileA + 32) * 128 + 64 + (x & 31)];
    }
    if (sA >= 0 && sB >= 0) unite_f(F, sA, sB);
}

// ============ phase C: fold donors (4 sub-blocks per region = 256 blocks) ==
__global__ void merge_frag_k(int* __restrict__ F, float* __restrict__ fragSums,
                             const int* __restrict__ fragCnt, int C) {
    int cidx = blockIdx.x >> 2, sub = blockIdx.x & 3;
    if (cidx >= C * 8) return;
    int cnt = fragCnt[cidx]; if (cnt > REGCAP) cnt = REGCAP;
    int quarter = (cnt + 3) >> 2;
    int lo = sub * quarter;
    int hi = lo + quarter; if (hi > cnt) hi = cnt;
    for (int off = lo + threadIdx.x; off < hi; off += 256) {
        int i = cidx * REGCAP + off;
        int rt = find_f(F, i);
        if (rt != i) {
            float2 d = ((const float2*)fragSums)[i];
            unsafeAtomicAdd(&fragSums[2 * rt], d.x);
            unsafeAtomicAdd(&fragSums[2 * rt + 1], d.y);
        }
    }
}

// ============ phase D: dice (4 sub-blocks per region), WRITE partials ======
__global__ void dice_frag_k(const int* __restrict__ F, const float2* __restrict__ fragSums,
                            const int* __restrict__ fragCnt,
                            float* __restrict__ partials, int b0, int C) {
    int cidx = blockIdx.x >> 2, sub = blockIdx.x & 3;
    if (cidx >= C * 8) return;
    int cnt = fragCnt[cidx]; if (cnt > REGCAP) cnt = REGCAP;
    int quarter = (cnt + 3) >> 2;
    int lo = sub * quarter;
    int hi = lo + quarter; if (hi > cnt) hi = cnt;
    float ds = 0.f, dn = 0.f;
    for (int off = lo + threadIdx.x; off < hi; off += 256) {
        int i = cidx * REGCAP + off;
        if (F[i] != i) continue;             // not a final root
        float2 s2 = fragSums[i];
        ds += (2.f * s2.x + 1e-6f) / (s2.y + 1e-6f);
        dn += 1.f;
    }
    #pragma unroll
    for (int d = 32; d > 0; d >>= 1) {
        ds += __shfl_down(ds, d);
        dn += __shfl_down(dn, d);
    }
    __shared__ float s_s[4], s_n[4];
    int wv = threadIdx.x >> 6;
    if ((threadIdx.x & 63) == 0) { s_s[wv] = ds; s_n[wv] = dn; }
    __syncthreads();
    if (threadIdx.x == 0) {
        int img = b0 + (cidx >> 3);
        int slotp = ((cidx & 7) << 2) | sub;     // 32 partial pairs per image
        partials[img * 64 + slotp * 2]     = s_s[0] + s_s[1] + s_s[2] + s_s[3];
        partials[img * 64 + slotp * 2 + 1] = s_n[0] + s_n[1] + s_n[2] + s_n[3];
    }
}

__global__ void zero_k(int* __restrict__ fragCnt) {
    if (threadIdx.x < NREG) fragCnt[threadIdx.x] = 0;
}

__global__ void final_k(const float* __restrict__ partials, float* __restrict__ out, int B) {
    if (threadIdx.x == 0 && blockIdx.x == 0) {
        float acc = 0.f;
        for (int img = 0; img < B; ++img) {
            float s = 0.f, n = 0.f;
            for (int p = 0; p < 32; ++p) {
                s += partials[img * 64 + p * 2];
                n += partials[img * 64 + p * 2 + 1];
            }
            acc += (n > 0.f) ? (1.f - s / n) : 1.f;
        }
        out[0] = acc / (float)B;
    }
}

// ============ launch ============
extern "C" void kernel_launch(void* const* d_in, const int* in_sizes, int n_in,
                              void* d_out, int out_size, void* d_ws, size_t ws_size,
                              hipStream_t stream) {
    const float* pred = (const float*)d_in[0];
    const float* targ = (const float*)d_in[1];
    float* out = (float*)d_out;
    int B = in_sizes[0] / NPIX;
    if (B < 1) B = 1;

    char* ws = (char*)d_ws;
    size_t off = 0;
    float* partials = (float*)ws;                       // B*64 floats
    off += ((size_t)B * 64 * sizeof(float) + 255) & ~(size_t)255;
    int* fragCnt = (int*)(ws + off);
    off += ((size_t)NREG * 4 + 255) & ~(size_t)255;

    // fixed slot pool: F 1MB + fragSums 2MB
    const size_t NSLOT = (size_t)NREG * REGCAP;
    int*    F        = (int*)   (ws + off); off += NSLOT * 4;
    float2* fragSums = (float2*)(ws + off); off += NSLOT * 8;
    size_t fixed = off;

    const size_t perImg = (size_t)1024 * 128 * 4;       // edges only (512KB)
    int maxC = 1;
    if (ws_size > fixed + perImg) {
        size_t mm = (ws_size - fixed) / perImg;
        maxC = (int)(mm < (size_t)B ? mm : (size_t)B);
        if (maxC < 1) maxC = 1;
        if (maxC > 8) maxC = 8;
    }
    int* edgesA = (int*)(ws + off);

    for (int b0 = 0; b0 < B; b0 += maxC) {
        int C = (B - b0 < maxC) ? (B - b0) : maxC;
        const float* pc = pred + (size_t)b0 * NPIX;
        const float* tc = targ + (size_t)b0 * NPIX;
        int nwg = C * 256;
        zero_k<<<1, 64, 0, stream>>>(fragCnt);
        local_k<<<nwg, 256, 0, stream>>>((const float4*)pc, (const float4*)tc,
                                         edgesA, F, fragSums, fragCnt, nwg);
        bound_k<<<C * 248, 256, 0, stream>>>(edgesA, F);
        merge_frag_k<<<NREG * 4, 256, 0, stream>>>(F, (float*)fragSums, fragCnt, C);
        dice_frag_k<<<NREG * 4, 256, 0, stream>>>(F, fragSums, fragCnt, partials, b0, C);
    }

    final_k<<<1, 64, 0, stream>>>(partials, out, B);
}